// Round 1
// baseline (190.827 us; speedup 1.0000x reference)
//
#include <hip/hip_runtime.h>
#include <hip/hip_bf16.h>
#include <math.h>

// Problem constants
#define BROWS 16384
#define IN_DIM 128
#define HID 512
#define ATT 256
#define KTOT 896          // IN_DIM + HID + ATT
#define KC_TOT 112        // KTOT / 8

typedef __bf16 bf16x8 __attribute__((ext_vector_type(8)));
typedef float f32x4 __attribute__((ext_vector_type(4)));

// ---------------------------------------------------------------------------
// Kernel 1: pack A (combined = [x_t | h_ltc | context]) fp32 -> bf16 into a
// pre-staged layout: A_stage[mt][kc][mi][8]  (16B chunks), so that the GEMM's
// global_load_lds staging is fully contiguous 1KB per instruction.
// Grid: (128 mt, 7 kb) x 256 threads. Each block: 128 rows x 128 k-cols.
// ---------------------------------------------------------------------------
__global__ void pack_A(const float* __restrict__ x, const float* __restrict__ h,
                       const float* __restrict__ ctx, __hip_bfloat16* __restrict__ A_stage) {
    const int mt = blockIdx.x;   // 0..127
    const int kb = blockIdx.y;   // 0..6  (each = 16 kc = 128 k)
    const float* src; int rs, c0;
    if (kb == 0)      { src = x;   rs = IN_DIM; c0 = 0; }
    else if (kb < 5)  { src = h;   rs = HID;    c0 = (kb - 1) * 128; }
    else              { src = ctx; rs = ATT;    c0 = (kb - 5) * 128; }

    __shared__ __attribute__((aligned(16))) __hip_bfloat16 tile[128][136]; // +8 pad

    const int tid = threadIdx.x;
    // Phase 1: coalesced fp32 reads -> bf16 -> LDS
    #pragma unroll
    for (int it = 0; it < 16; ++it) {
        int lin = it * 256 + tid;        // 4096 float4 chunks
        int mi = lin >> 5;               // 128 rows
        int c4 = lin & 31;               // 32 float4 per row
        float4 v = *(const float4*)(src + (size_t)(mt * 128 + mi) * rs + c0 + c4 * 4);
        union { __hip_bfloat16 hh[4]; ushort4 u; } p;
        p.hh[0] = __float2bfloat16(v.x);
        p.hh[1] = __float2bfloat16(v.y);
        p.hh[2] = __float2bfloat16(v.z);
        p.hh[3] = __float2bfloat16(v.w);
        *(ushort4*)&tile[mi][c4 * 4] = p.u;
    }
    __syncthreads();
    // Phase 2: write staged 16B chunks, coalesced
    #pragma unroll
    for (int it = 0; it < 8; ++it) {
        int lin = it * 256 + tid;        // 2048 chunks: kcl*128 + mi
        int kcl = lin >> 7;              // 0..15
        int mi  = lin & 127;
        uint4 vv = *(const uint4*)&tile[mi][kcl * 8];
        *(uint4*)(A_stage + ((size_t)(mt * KC_TOT + kb * 16 + kcl) * 128 + mi) * 8) = vv;
    }
}

// ---------------------------------------------------------------------------
// Kernel 2: pack augmented weights -> B_stage[jt][kc][nl][8] bf16 and dconst.
// nl in [0,96): jg = nl/48, type = (nl%48)/16 (0=gate,1=dyn,2=tau), j16 = nl%16
// j = jt*32 + jg*16 + j16.  type2 rows are W_tau over k in [128,640), else 0.
// ---------------------------------------------------------------------------
__device__ __forceinline__ float softplus_f(float x) {
    return fmaxf(x, 0.0f) + log1pf(__expf(-fabsf(x)));
}

__global__ void pack_B(const float* __restrict__ W_gd, const float* __restrict__ W_tau,
                       const float* __restrict__ gleak, const float* __restrict__ cm,
                       __hip_bfloat16* __restrict__ B_stage, float* __restrict__ dconst) {
    const int cid = blockIdx.x * 256 + threadIdx.x;   // 672*256 = 172032 exactly
    if (cid < HID) {
        dconst[cid] = softplus_f(cm[cid]) + softplus_f(gleak[cid]) + 1e-6f;
    }
    const int nl = cid % 96;
    const int kc = (cid / 96) % KC_TOT;
    const int jt = cid / (96 * KC_TOT);
    const int jg = nl / 48, type = (nl % 48) / 16, j16 = nl % 16;
    const int j = jt * 32 + jg * 16 + j16;
    const int k0 = kc * 8;

    float v[8];
    if (type == 0) {
        const float* s = W_gd + (size_t)j * KTOT + k0;
        #pragma unroll
        for (int i = 0; i < 8; ++i) v[i] = s[i];
    } else if (type == 1) {
        const float* s = W_gd + (size_t)(HID + j) * KTOT + k0;
        #pragma unroll
        for (int i = 0; i < 8; ++i) v[i] = s[i];
    } else {
        if (k0 >= IN_DIM && k0 < IN_DIM + HID) {
            const float* s = W_tau + (size_t)j * HID + (k0 - IN_DIM);
            #pragma unroll
            for (int i = 0; i < 8; ++i) v[i] = s[i];
        } else {
            #pragma unroll
            for (int i = 0; i < 8; ++i) v[i] = 0.0f;
        }
    }
    union { __hip_bfloat16 hh[8]; uint4 u; } p;
    #pragma unroll
    for (int i = 0; i < 8; ++i) p.hh[i] = __float2bfloat16(v[i]);
    *(uint4*)(B_stage + (size_t)cid * 8) = p.u;
}

// ---------------------------------------------------------------------------
// Kernel 3: fused GEMM + epilogue.
// Block tile: 128(M) x 32(j) x {gate,dyn,tau}. 4 waves (2M x 2J). BK=64.
// Grid: 128 mt * 16 jt = 2048 blocks x 256 threads.
// LDS: As = 8kc x 128mi x 16B = 16KB ; Bs = 8kc x 96nl x 16B = 12KB.
// ---------------------------------------------------------------------------
__global__ __launch_bounds__(256, 2) void ltc_gemm(
    const __hip_bfloat16* __restrict__ A_stage, const __hip_bfloat16* __restrict__ B_stage,
    const float* __restrict__ h_ltc, const float* __restrict__ b_gd,
    const float* __restrict__ b_tau, const float* __restrict__ dconst,
    float* __restrict__ out) {

    __shared__ __attribute__((aligned(16))) char smem[16384 + 12288];
    char* As = smem;
    char* Bs = smem + 16384;

    const int bx = blockIdx.x;
    const int jt = bx & 15;     // 0..15
    const int mt = bx >> 4;     // 0..127
    const int tid = threadIdx.x;
    const int wave = tid >> 6, lane = tid & 63;
    const int wm = wave >> 1;   // 0..1  M half
    const int wj = wave & 1;    // 0..1  j group
    const int q = lane >> 4, t = lane & 15;

    f32x4 accg[4], accd[4], acct[4];
    #pragma unroll
    for (int i = 0; i < 4; ++i) { accg[i] = (f32x4)0.0f; accd[i] = (f32x4)0.0f; acct[i] = (f32x4)0.0f; }

    // Staging pointers (this wave's chunks): A chunks {wave+4r, r<4}, B chunks {wave+4r, r<3}
    const __hip_bfloat16* aSrc[4]; char* aDst[4];
    #pragma unroll
    for (int r = 0; r < 4; ++r) {
        int c = wave + 4 * r;
        int kcl = c >> 1, half = c & 1;
        aSrc[r] = A_stage + ((size_t)(mt * KC_TOT + kcl) * 128 + half * 64 + lane) * 8;
        aDst[r] = As + c * 1024;
    }
    const __hip_bfloat16* bSrc[3]; char* bDst[3];
    #pragma unroll
    for (int r = 0; r < 3; ++r) {
        int c = wave + 4 * r;
        bSrc[r] = B_stage + (size_t)jt * (KC_TOT * 768) + c * 512 + lane * 8;
        bDst[r] = Bs + c * 1024;
    }

    for (int ks = 0; ks < 14; ++ks) {
        // stage next K-slab (BK=64): A 16KB, B 12KB via global_load_lds width=16
        #pragma unroll
        for (int r = 0; r < 4; ++r)
            __builtin_amdgcn_global_load_lds(
                (const __attribute__((address_space(1))) void*)aSrc[r],
                (__attribute__((address_space(3))) void*)aDst[r], 16, 0, 0);
        #pragma unroll
        for (int r = 0; r < 3; ++r)
            __builtin_amdgcn_global_load_lds(
                (const __attribute__((address_space(1))) void*)bSrc[r],
                (__attribute__((address_space(3))) void*)bDst[r], 16, 0, 0);
        __syncthreads();   // drains vmcnt before compute

        const bool tau_on = (ks >= 2 && ks < 10);  // k in [128,640)
        #pragma unroll
        for (int ko2 = 0; ko2 < 2; ++ko2) {
            const char* ab = As + (((ko2 * 4 + q) * 128 + wm * 64 + t) << 4);
            bf16x8 a0 = *(const bf16x8*)(ab);
            bf16x8 a1 = *(const bf16x8*)(ab + 256);
            bf16x8 a2 = *(const bf16x8*)(ab + 512);
            bf16x8 a3 = *(const bf16x8*)(ab + 768);
            const char* bb = Bs + (((ko2 * 4 + q) * 96 + wj * 48 + t) << 4);
            bf16x8 bg = *(const bf16x8*)(bb);
            bf16x8 bd = *(const bf16x8*)(bb + 256);
            accg[0] = __builtin_amdgcn_mfma_f32_16x16x32_bf16(a0, bg, accg[0], 0, 0, 0);
            accg[1] = __builtin_amdgcn_mfma_f32_16x16x32_bf16(a1, bg, accg[1], 0, 0, 0);
            accg[2] = __builtin_amdgcn_mfma_f32_16x16x32_bf16(a2, bg, accg[2], 0, 0, 0);
            accg[3] = __builtin_amdgcn_mfma_f32_16x16x32_bf16(a3, bg, accg[3], 0, 0, 0);
            accd[0] = __builtin_amdgcn_mfma_f32_16x16x32_bf16(a0, bd, accd[0], 0, 0, 0);
            accd[1] = __builtin_amdgcn_mfma_f32_16x16x32_bf16(a1, bd, accd[1], 0, 0, 0);
            accd[2] = __builtin_amdgcn_mfma_f32_16x16x32_bf16(a2, bd, accd[2], 0, 0, 0);
            accd[3] = __builtin_amdgcn_mfma_f32_16x16x32_bf16(a3, bd, accd[3], 0, 0, 0);
            if (tau_on) {
                bf16x8 bt = *(const bf16x8*)(bb + 512);
                acct[0] = __builtin_amdgcn_mfma_f32_16x16x32_bf16(a0, bt, acct[0], 0, 0, 0);
                acct[1] = __builtin_amdgcn_mfma_f32_16x16x32_bf16(a1, bt, acct[1], 0, 0, 0);
                acct[2] = __builtin_amdgcn_mfma_f32_16x16x32_bf16(a2, bt, acct[2], 0, 0, 0);
                acct[3] = __builtin_amdgcn_mfma_f32_16x16x32_bf16(a3, bt, acct[3], 0, 0, 0);
            }
        }
        #pragma unroll
        for (int r = 0; r < 4; ++r) aSrc[r] += 8192;   // 8 kc * 128 mi * 8 elems
        #pragma unroll
        for (int r = 0; r < 3; ++r) bSrc[r] += 6144;   // 8 kc * 96 nl * 8 elems
        __syncthreads();   // protect LDS before next stage
    }

    // Epilogue: fused bias + sigmoid/tanh/softplus + divide, in-register.
    const int j = jt * 32 + wj * 16 + t;
    const float bgj = b_gd[j];
    const float bdj = b_gd[HID + j];
    const float btj = b_tau[j];
    const float dcj = dconst[j];
    const int row0 = mt * 128 + wm * 64 + q * 4;
    #pragma unroll
    for (int i = 0; i < 4; ++i) {
        #pragma unroll
        for (int r = 0; r < 4; ++r) {
            const int row = row0 + i * 16 + r;
            const float g  = accg[i][r] + bgj;
            const float d  = accd[i][r] + bdj;
            const float tp = acct[i][r] + btj;
            const float h  = h_ltc[(size_t)row * HID + j];
            const float sig = 1.0f / (1.0f + __expf(-g));
            const float th  = tanhf(d);
            const float tau = fmaxf(tp, 0.0f) + log1pf(__expf(-fabsf(tp)));
            out[(size_t)row * HID + j] = (sig * th - h) / (tau + dcj);
        }
    }
}

// ---------------------------------------------------------------------------
extern "C" void kernel_launch(void* const* d_in, const int* in_sizes, int n_in,
                              void* d_out, int out_size, void* d_ws, size_t ws_size,
                              hipStream_t stream) {
    // setup_inputs order: t, h_ltc, x_t, context, W_gd, b_gd, W_tau, b_tau, gleak, cm
    const float* h_ltc = (const float*)d_in[1];
    const float* x_t   = (const float*)d_in[2];
    const float* ctx   = (const float*)d_in[3];
    const float* W_gd  = (const float*)d_in[4];
    const float* b_gd  = (const float*)d_in[5];
    const float* W_tau = (const float*)d_in[6];
    const float* b_tau = (const float*)d_in[7];
    const float* gleak = (const float*)d_in[8];
    const float* cm    = (const float*)d_in[9];

    char* ws = (char*)d_ws;
    __hip_bfloat16* A_stage = (__hip_bfloat16*)ws;                       // 128*112*128*16 = 29,360,128 B
    __hip_bfloat16* B_stage = (__hip_bfloat16*)(ws + 29360128);          // 16*112*96*16  =  2,752,512 B
    float* dconst = (float*)(ws + 29360128 + 2752512);                   // 2048 B

    pack_A<<<dim3(128, 7), 256, 0, stream>>>(x_t, h_ltc, ctx, A_stage);
    pack_B<<<672, 256, 0, stream>>>(W_gd, W_tau, gleak, cm, B_stage, dconst);
    ltc_gemm<<<2048, 256, 0, stream>>>(A_stage, B_stage, h_ltc, b_gd, b_tau, dconst,
                                       (float*)d_out);
}

// Round 2
// 170.688 us; speedup vs baseline: 1.1180x; 1.1180x over previous
//
#include <hip/hip_runtime.h>
#include <hip/hip_bf16.h>
#include <math.h>

// Problem constants
#define BROWS 16384
#define IN_DIM 128
#define HID 512
#define ATT 256
#define KTOT 896          // IN_DIM + HID + ATT
#define KC_TOT 112        // KTOT / 8

typedef __bf16 bf16x8 __attribute__((ext_vector_type(8)));
typedef float f32x4 __attribute__((ext_vector_type(4)));

// ---------------------------------------------------------------------------
// Kernel 1: pack A (combined = [x_t | h_ltc | context]) fp32 -> bf16 into
// A_stage[mt][kc][mi][8] (16B chunks) so GEMM staging is contiguous 1KB/instr.
// Grid: (128 mt, 7 kb) x 256. blockIdx linear % 8 == mt % 8 -> same XCD as
// the GEMM blocks that consume tile mt (producer/consumer L2 locality).
// ---------------------------------------------------------------------------
__global__ void pack_A(const float* __restrict__ x, const float* __restrict__ h,
                       const float* __restrict__ ctx, __hip_bfloat16* __restrict__ A_stage) {
    const int mt = blockIdx.x;   // 0..127
    const int kb = blockIdx.y;   // 0..6  (each = 16 kc = 128 k)
    const float* src; int rs, c0;
    if (kb == 0)      { src = x;   rs = IN_DIM; c0 = 0; }
    else if (kb < 5)  { src = h;   rs = HID;    c0 = (kb - 1) * 128; }
    else              { src = ctx; rs = ATT;    c0 = (kb - 5) * 128; }

    __shared__ __attribute__((aligned(16))) __hip_bfloat16 tile[128][136]; // +8 pad

    const int tid = threadIdx.x;
    #pragma unroll
    for (int it = 0; it < 16; ++it) {
        int lin = it * 256 + tid;        // 4096 float4 chunks
        int mi = lin >> 5;               // 128 rows
        int c4 = lin & 31;               // 32 float4 per row
        float4 v = *(const float4*)(src + (size_t)(mt * 128 + mi) * rs + c0 + c4 * 4);
        union { __hip_bfloat16 hh[4]; ushort4 u; } p;
        p.hh[0] = __float2bfloat16(v.x);
        p.hh[1] = __float2bfloat16(v.y);
        p.hh[2] = __float2bfloat16(v.z);
        p.hh[3] = __float2bfloat16(v.w);
        *(ushort4*)&tile[mi][c4 * 4] = p.u;
    }
    __syncthreads();
    #pragma unroll
    for (int it = 0; it < 8; ++it) {
        int lin = it * 256 + tid;        // 2048 chunks: kcl*128 + mi
        int kcl = lin >> 7;
        int mi  = lin & 127;
        uint4 vv = *(const uint4*)&tile[mi][kcl * 8];
        *(uint4*)(A_stage + ((size_t)(mt * KC_TOT + kb * 16 + kcl) * 128 + mi) * 8) = vv;
    }
}

// ---------------------------------------------------------------------------
// Kernel 2: pack augmented weights -> B_stage[jt(8)][kc(112)][nl(192)][8] bf16.
// nl = jg*48 + type*16 + j16 ; jg in [0,4), type 0=gate 1=dyn 2=tau.
// j = jt*64 + jg*16 + j16. tau rows nonzero only for k in [128,640).
// ---------------------------------------------------------------------------
__device__ __forceinline__ float softplus_f(float x) {
    return fmaxf(x, 0.0f) + log1pf(__expf(-fabsf(x)));
}

__global__ void pack_B(const float* __restrict__ W_gd, const float* __restrict__ W_tau,
                       const float* __restrict__ gleak, const float* __restrict__ cm,
                       __hip_bfloat16* __restrict__ B_stage, float* __restrict__ dconst) {
    const int cid = blockIdx.x * 256 + threadIdx.x;   // 672*256 = 172032 exactly
    if (cid < HID) {
        dconst[cid] = softplus_f(cm[cid]) + softplus_f(gleak[cid]) + 1e-6f;
    }
    const int nl = cid % 192;
    const int kc = (cid / 192) % KC_TOT;
    const int jt = cid / (192 * KC_TOT);
    const int jg = nl / 48, type = (nl % 48) / 16, j16 = nl % 16;
    const int j = jt * 64 + jg * 16 + j16;
    const int k0 = kc * 8;

    float v[8];
    if (type == 0) {
        const float* s = W_gd + (size_t)j * KTOT + k0;
        #pragma unroll
        for (int i = 0; i < 8; ++i) v[i] = s[i];
    } else if (type == 1) {
        const float* s = W_gd + (size_t)(HID + j) * KTOT + k0;
        #pragma unroll
        for (int i = 0; i < 8; ++i) v[i] = s[i];
    } else {
        if (k0 >= IN_DIM && k0 < IN_DIM + HID) {
            const float* s = W_tau + (size_t)j * HID + (k0 - IN_DIM);
            #pragma unroll
            for (int i = 0; i < 8; ++i) v[i] = s[i];
        } else {
            #pragma unroll
            for (int i = 0; i < 8; ++i) v[i] = 0.0f;
        }
    }
    union { __hip_bfloat16 hh[8]; uint4 u; } p;
    #pragma unroll
    for (int i = 0; i < 8; ++i) p.hh[i] = __float2bfloat16(v[i]);
    *(uint4*)(B_stage + (size_t)cid * 8) = p.u;
}

// ---------------------------------------------------------------------------
// Kernel 3: fused GEMM + epilogue.
// Block tile: 128(M) x 64(j) x {gate,dyn,tau}. 4 waves (2M x 2Jg). BK=64.
// Grid: 1024 blocks (mt = bx & 127 -> A-tile siblings co-XCD). 256 threads.
// LDS: As = 8kc x 128mi x 16B = 16KB ; Bs = 8kc x 192nl x 16B = 24KB.
// ---------------------------------------------------------------------------
__global__ __launch_bounds__(256, 2) void ltc_gemm(
    const __hip_bfloat16* __restrict__ A_stage, const __hip_bfloat16* __restrict__ B_stage,
    const float* __restrict__ h_ltc, const float* __restrict__ b_gd,
    const float* __restrict__ b_tau, const float* __restrict__ dconst,
    float* __restrict__ out) {

    __shared__ __attribute__((aligned(16))) char smem[16384 + 24576];
    char* As = smem;
    char* Bs = smem + 16384;

    const int bx = blockIdx.x;
    const int mt = bx & 127;    // A-tile id; bx % 8 == mt % 8 -> same XCD as pack_A writer
    const int jt = bx >> 7;     // 0..7
    const int tid = threadIdx.x;
    const int wave = tid >> 6, lane = tid & 63;
    const int wm = wave >> 1;   // 0..1  M half (64 rows)
    const int wj = wave & 1;    // 0..1  jg pair (32 j)
    const int q = lane >> 4, t = lane & 15;

    f32x4 accg[2][4], accd[2][4], acct[2][4];
    #pragma unroll
    for (int g = 0; g < 2; ++g)
        #pragma unroll
        for (int i = 0; i < 4; ++i) {
            accg[g][i] = (f32x4)0.0f; accd[g][i] = (f32x4)0.0f; acct[g][i] = (f32x4)0.0f;
        }

    // Staging: A = 16 chunks of 1KB, B = 24 chunks. Wave handles A{wave+4r,r<4},
    // B{wave+4r,r<6}.
    const __hip_bfloat16* aSrc[4]; char* aDst[4];
    #pragma unroll
    for (int r = 0; r < 4; ++r) {
        int c = wave + 4 * r;
        int kcl = c >> 1, half = c & 1;
        aSrc[r] = A_stage + ((size_t)(mt * KC_TOT + kcl) * 128 + half * 64 + lane) * 8;
        aDst[r] = As + c * 1024;
    }
    const __hip_bfloat16* bSrc[6]; char* bDst[6];
    #pragma unroll
    for (int r = 0; r < 6; ++r) {
        int c = wave + 4 * r;
        bSrc[r] = B_stage + (size_t)jt * (KC_TOT * 1536) + c * 512 + lane * 8;
        bDst[r] = Bs + c * 1024;
    }

    for (int ks = 0; ks < 14; ++ks) {
        #pragma unroll
        for (int r = 0; r < 4; ++r)
            __builtin_amdgcn_global_load_lds(
                (const __attribute__((address_space(1))) void*)aSrc[r],
                (__attribute__((address_space(3))) void*)aDst[r], 16, 0, 0);
        #pragma unroll
        for (int r = 0; r < 6; ++r)
            __builtin_amdgcn_global_load_lds(
                (const __attribute__((address_space(1))) void*)bSrc[r],
                (__attribute__((address_space(3))) void*)bDst[r], 16, 0, 0);
        __syncthreads();

        const bool tau_on = (ks >= 2 && ks < 10);  // k in [128,640)
        #pragma unroll
        for (int ko2 = 0; ko2 < 2; ++ko2) {
            const int kcl = ko2 * 4 + q;
            const char* ab = As + (((kcl * 128) + wm * 64 + t) << 4);
            bf16x8 a0 = *(const bf16x8*)(ab);
            bf16x8 a1 = *(const bf16x8*)(ab + 256);
            bf16x8 a2 = *(const bf16x8*)(ab + 512);
            bf16x8 a3 = *(const bf16x8*)(ab + 768);
            #pragma unroll
            for (int g = 0; g < 2; ++g) {
                const char* bb = Bs + (((kcl * 192) + wj * 96 + g * 48 + t) << 4);
                bf16x8 bg = *(const bf16x8*)(bb);
                bf16x8 bd = *(const bf16x8*)(bb + 256);
                accg[g][0] = __builtin_amdgcn_mfma_f32_16x16x32_bf16(a0, bg, accg[g][0], 0, 0, 0);
                accg[g][1] = __builtin_amdgcn_mfma_f32_16x16x32_bf16(a1, bg, accg[g][1], 0, 0, 0);
                accg[g][2] = __builtin_amdgcn_mfma_f32_16x16x32_bf16(a2, bg, accg[g][2], 0, 0, 0);
                accg[g][3] = __builtin_amdgcn_mfma_f32_16x16x32_bf16(a3, bg, accg[g][3], 0, 0, 0);
                accd[g][0] = __builtin_amdgcn_mfma_f32_16x16x32_bf16(a0, bd, accd[g][0], 0, 0, 0);
                accd[g][1] = __builtin_amdgcn_mfma_f32_16x16x32_bf16(a1, bd, accd[g][1], 0, 0, 0);
                accd[g][2] = __builtin_amdgcn_mfma_f32_16x16x32_bf16(a2, bd, accd[g][2], 0, 0, 0);
                accd[g][3] = __builtin_amdgcn_mfma_f32_16x16x32_bf16(a3, bd, accd[g][3], 0, 0, 0);
                if (tau_on) {
                    bf16x8 bt = *(const bf16x8*)(bb + 512);
                    acct[g][0] = __builtin_amdgcn_mfma_f32_16x16x32_bf16(a0, bt, acct[g][0], 0, 0, 0);
                    acct[g][1] = __builtin_amdgcn_mfma_f32_16x16x32_bf16(a1, bt, acct[g][1], 0, 0, 0);
                    acct[g][2] = __builtin_amdgcn_mfma_f32_16x16x32_bf16(a2, bt, acct[g][2], 0, 0, 0);
                    acct[g][3] = __builtin_amdgcn_mfma_f32_16x16x32_bf16(a3, bt, acct[g][3], 0, 0, 0);
                }
            }
        }
        #pragma unroll
        for (int r = 0; r < 4; ++r) aSrc[r] += 8192;    // 8 kc * 128 * 8
        #pragma unroll
        for (int r = 0; r < 6; ++r) bSrc[r] += 12288;   // 8 kc * 192 * 8
        __syncthreads();
    }

    // Epilogue: bias + sigmoid/tanh/softplus + divide, fast-math intrinsics.
    const int row0 = mt * 128 + wm * 64 + q * 4;
    #pragma unroll
    for (int g = 0; g < 2; ++g) {
        const int j = jt * 64 + (wj * 2 + g) * 16 + t;
        const float bgj = b_gd[j];
        const float bdj = b_gd[HID + j];
        const float btj = b_tau[j];
        const float dcj = dconst[j];
        #pragma unroll
        for (int i = 0; i < 4; ++i) {
            #pragma unroll
            for (int r = 0; r < 4; ++r) {
                const int row = row0 + i * 16 + r;
                const float gv = accg[g][i][r] + bgj;
                const float dv = accd[g][i][r] + bdj;
                const float tp = acct[g][i][r] + btj;
                const float h  = h_ltc[(size_t)row * HID + j];
                const float sig = __builtin_amdgcn_rcpf(1.0f + __expf(-gv));
                const float th  = 1.0f - 2.0f * __builtin_amdgcn_rcpf(__expf(2.0f * dv) + 1.0f);
                const float tau = fmaxf(tp, 0.0f) + __logf(1.0f + __expf(-fabsf(tp)));
                out[(size_t)row * HID + j] = (sig * th - h) * __builtin_amdgcn_rcpf(tau + dcj);
            }
        }
    }
}

// ---------------------------------------------------------------------------
extern "C" void kernel_launch(void* const* d_in, const int* in_sizes, int n_in,
                              void* d_out, int out_size, void* d_ws, size_t ws_size,
                              hipStream_t stream) {
    // setup_inputs order: t, h_ltc, x_t, context, W_gd, b_gd, W_tau, b_tau, gleak, cm
    const float* h_ltc = (const float*)d_in[1];
    const float* x_t   = (const float*)d_in[2];
    const float* ctx   = (const float*)d_in[3];
    const float* W_gd  = (const float*)d_in[4];
    const float* b_gd  = (const float*)d_in[5];
    const float* W_tau = (const float*)d_in[6];
    const float* b_tau = (const float*)d_in[7];
    const float* gleak = (const float*)d_in[8];
    const float* cm    = (const float*)d_in[9];

    char* ws = (char*)d_ws;
    __hip_bfloat16* A_stage = (__hip_bfloat16*)ws;                       // 29,360,128 B
    __hip_bfloat16* B_stage = (__hip_bfloat16*)(ws + 29360128);          //  2,752,512 B
    float* dconst = (float*)(ws + 29360128 + 2752512);                   //      2,048 B

    pack_B<<<672, 256, 0, stream>>>(W_gd, W_tau, gleak, cm, B_stage, dconst);
    pack_A<<<dim3(128, 7), 256, 0, stream>>>(x_t, h_ltc, ctx, A_stage);
    ltc_gemm<<<1024, 256, 0, stream>>>(A_stage, B_stage, h_ltc, b_gd, b_tau, dconst,
                                       (float*)d_out);
}